// Round 1
// baseline (144.748 us; speedup 1.0000x reference)
//
#include <hip/hip_runtime.h>
#include <hip/hip_bf16.h>

// Shapes (fixed by reference): b=2, h=8, t=8192, dh=128
#define T_SEQ   8192
#define DH      128
#define NBH     16
#define NBUCK   128
#define BSZ     64
#define EPSF    1e-6f

typedef __attribute__((ext_vector_type(8))) __bf16 bf16x8;
typedef __attribute__((ext_vector_type(4))) float  f32x4;

static __device__ __forceinline__ unsigned short f2bf(float f) {
  __bf16 h = (__bf16)f;
  return __builtin_bit_cast(unsigned short, h);
}

// ---------------------------------------------------------------------------
// Kernel A: per-bucket q/k sums -> sortnet linear (fp32) -> relu -> gumbel log
// grid (128, 16), 256 threads. Writes rbuf[bh][u][v] (pre-sinkhorn log-space).
// ---------------------------------------------------------------------------
__global__ __launch_bounds__(256) void k_sortnet(
    const float* __restrict__ q, const float* __restrict__ k,
    const float* __restrict__ W, const float* __restrict__ ug,
    float* __restrict__ rbuf) {
  const int u  = blockIdx.x;
  const int bh = blockIdx.y;
  const int t  = threadIdx.x;
  __shared__ float x[256];
  __shared__ float part[256];
  {
    const float* src = (t < 128) ? q : k;
    const int col = t & 127;
    size_t base = ((size_t)bh * T_SEQ + (size_t)u * BSZ) * DH + col;
    float acc = 0.f;
    #pragma unroll 8
    for (int r = 0; r < BSZ; r++) acc += src[base + (size_t)r * DH];
    x[t] = acc;
  }
  __syncthreads();
  {
    const int vcol = t & 127;
    const int eh = t >> 7;   // 0/1: split the 256-long dot across two thread halves
    const float* Wp = W + ((size_t)(bh & 7) * 256 + (size_t)eh * 128) * NBUCK + vcol;
    float racc = 0.f;
    #pragma unroll 8
    for (int e = 0; e < 128; e++) racc += x[eh * 128 + e] * Wp[(size_t)e * NBUCK];
    part[t] = racc;
  }
  __syncthreads();
  if (t < 128) {
    float R = part[t] + part[t + 128];
    R = fmaxf(R, 0.f) + EPSF;
    float gu = ug[((size_t)bh * NBUCK + u) * NBUCK + t] + EPSF;
    float g = -logf(-logf(gu) + EPSF);
    rbuf[((size_t)bh * NBUCK + u) * NBUCK + t] = (logf(R) + g) * (1.f / 0.75f);
  }
}

// ---------------------------------------------------------------------------
// Kernel B: sinkhorn (7 iters) in log space via row/col offset vectors, then
// per-row argmax -> idx, scale s = exp(r+ra+ca). grid 16, 512 threads.
// Effective matrix: r0[u][v] + ra[u] + ca[v]; never rewrites r0.
// ---------------------------------------------------------------------------
__global__ __launch_bounds__(512) void k_sinkhorn(
    const float* __restrict__ rbuf, int* __restrict__ idxb, float* __restrict__ sb) {
  const int bh = blockIdx.x;
  const int t  = threadIdx.x;
  const int lane = t & 127;
  const int qt = t >> 7;            // quarter 0..3, 32 elems each
  __shared__ float rl[128 * 129];
  __shared__ float ca[128], ra[128], mred[128];
  __shared__ float pm[4 * 128], ps[4 * 128];
  __shared__ float bv[4 * 128];
  __shared__ int   bidx[4 * 128];

  const float* rb = rbuf + (size_t)bh * (NBUCK * NBUCK);
  for (int i = t; i < NBUCK * NBUCK; i += 512)
    rl[(i >> 7) * 129 + (i & 127)] = rb[i];
  if (t < 128) ca[t] = 0.f;
  __syncthreads();

  for (int iter = 0; iter < 7; iter++) {
    // --- row phase: ra[u] = -LSE_v( r0[u][v] + ca[v] ) ---
    {
      const int u = lane;
      float m = -1e30f;
      #pragma unroll 8
      for (int i = 0; i < 32; i++) { int v = qt * 32 + i; m = fmaxf(m, rl[u * 129 + v] + ca[v]); }
      pm[qt * 128 + u] = m;
      __syncthreads();
      if (t < 128) mred[t] = fmaxf(fmaxf(pm[t], pm[128 + t]), fmaxf(pm[256 + t], pm[384 + t]));
      __syncthreads();
      float mm = mred[u];
      float sum = 0.f;
      #pragma unroll 8
      for (int i = 0; i < 32; i++) { int v = qt * 32 + i; sum += __expf(rl[u * 129 + v] + ca[v] - mm); }
      ps[qt * 128 + u] = sum;
      __syncthreads();
      if (t < 128) ra[t] = -(mred[t] + logf(ps[t] + ps[128 + t] + ps[256 + t] + ps[384 + t]));
      __syncthreads();
    }
    // --- col phase: ca[v] = -LSE_u( r0[u][v] + ra[u] ) ---
    {
      const int v = lane;
      float m = -1e30f;
      #pragma unroll 8
      for (int i = 0; i < 32; i++) { int uu = qt * 32 + i; m = fmaxf(m, rl[uu * 129 + v] + ra[uu]); }
      pm[qt * 128 + v] = m;
      __syncthreads();
      if (t < 128) mred[t] = fmaxf(fmaxf(pm[t], pm[128 + t]), fmaxf(pm[256 + t], pm[384 + t]));
      __syncthreads();
      float mm = mred[v];
      float sum = 0.f;
      #pragma unroll 8
      for (int i = 0; i < 32; i++) { int uu = qt * 32 + i; sum += __expf(rl[uu * 129 + v] + ra[uu] - mm); }
      ps[qt * 128 + v] = sum;
      __syncthreads();
      if (t < 128) ca[t] = -(mred[t] + logf(ps[t] + ps[128 + t] + ps[256 + t] + ps[384 + t]));
      __syncthreads();
    }
  }

  // --- per-row argmax over v of r0[u][v] + ca[v] (ra[u] constant per row) ---
  {
    const int u = lane;
    float best = -1e30f; int bi = qt * 32;
    for (int i = 0; i < 32; i++) {
      int v = qt * 32 + i;
      float val = rl[u * 129 + v] + ca[v];
      if (val > best) { best = val; bi = v; }
    }
    bv[qt * 128 + u] = best; bidx[qt * 128 + u] = bi;
  }
  __syncthreads();
  if (t < 128) {
    float B = bv[t]; int I = bidx[t];
    #pragma unroll
    for (int q2 = 1; q2 < 4; q2++) {
      float val = bv[q2 * 128 + t];
      if (val > B) { B = val; I = bidx[q2 * 128 + t]; }
    }
    idxb[bh * NBUCK + t] = I;
    sb[bh * NBUCK + t] = expf(rl[t * 129 + I] + ra[t] + ca[I]);
  }
}

// ---------------------------------------------------------------------------
// Kernel C: per-bucket attention. grid (128,16), 256 threads (4 waves).
// Kcat = [s*K[vidx], K[u]] (s folded into logits), Vcat = [s*V[vidx], V[u]]
// (s folded into P post-softmax). bf16 MFMA 16x16x32; fp32 softmax.
// LDS: Kb[128][128] bf16 swizzled @0; Vt[128][128] (transposed) @16384;
//      P[64][128] reuses Kb region after barrier. XOR-swizzle ((row&7)<<3).
// ---------------------------------------------------------------------------
__global__ __launch_bounds__(256) void k_attn(
    const float* __restrict__ q, const float* __restrict__ k, const float* __restrict__ v,
    const int* __restrict__ idxb, const float* __restrict__ sb, float* __restrict__ out) {
  const int u  = blockIdx.x;
  const int bh = blockIdx.y;
  const int t  = threadIdx.x;
  const int lane = t & 63;
  const int w  = t >> 6;          // wave 0..3, owns output rows 16w..16w+15
  const int l15 = lane & 15;
  const int lgp = lane >> 4;      // 0..3

  __shared__ uint4 smem4[4096];   // 64 KB
  unsigned short* sm = (unsigned short*)smem4;

  const int   vidx = idxb[bh * NBUCK + u];
  const float sval = sb[bh * NBUCK + u];
  const size_t hb = (size_t)bh * (T_SEQ * DH);
  const float* qg = q + hb;
  const float* kg = k + hb;
  const float* vg = v + hb;

  // ---- stage K rows (0..63 = vidx bucket, 64..127 = u bucket), row-major ----
  #pragma unroll
  for (int it = 0; it < 16; it++) {
    int i = it * 256 + t;
    int row = i >> 5;
    int c4 = (i & 31) << 2;
    int grow = (row < 64) ? (vidx * BSZ + row) : (u * BSZ + (row - 64));
    float4 val = *(const float4*)(kg + (size_t)grow * DH + c4);
    ushort4 hh;
    hh.x = f2bf(val.x); hh.y = f2bf(val.y); hh.z = f2bf(val.z); hh.w = f2bf(val.w);
    *(ushort4*)(sm + (((row * 128 + c4) ^ ((row & 7) << 3)))) = hh;
  }
  // ---- stage V transposed: Vt[d][j] ----
  #pragma unroll
  for (int it = 0; it < 16; it++) {
    int i = it * 256 + t;
    int j = i & 127;
    int d0 = (i >> 7) << 2;
    int grow = (j < 64) ? (vidx * BSZ + j) : (u * BSZ + (j - 64));
    float4 val = *(const float4*)(vg + (size_t)grow * DH + d0);
    sm[16384 + (((d0 + 0) * 128 + j) ^ (((d0 + 0) & 7) << 3))] = f2bf(val.x);
    sm[16384 + (((d0 + 1) * 128 + j) ^ (((d0 + 1) & 7) << 3))] = f2bf(val.y);
    sm[16384 + (((d0 + 2) * 128 + j) ^ (((d0 + 2) & 7) << 3))] = f2bf(val.z);
    sm[16384 + (((d0 + 3) * 128 + j) ^ (((d0 + 3) & 7) << 3))] = f2bf(val.w);
  }

  // ---- Q A-fragments direct global -> reg (rows 16w + l15) ----
  bf16x8 aQ[4];
  {
    int qrow = u * BSZ + w * 16 + l15;
    const float* qp = qg + (size_t)qrow * DH + lgp * 8;
    #pragma unroll
    for (int kk = 0; kk < 4; kk++) {
      float4 v0 = *(const float4*)(qp + kk * 32);
      float4 v1 = *(const float4*)(qp + kk * 32 + 4);
      bf16x8 f;
      f[0] = (__bf16)v0.x; f[1] = (__bf16)v0.y; f[2] = (__bf16)v0.z; f[3] = (__bf16)v0.w;
      f[4] = (__bf16)v1.x; f[5] = (__bf16)v1.y; f[6] = (__bf16)v1.z; f[7] = (__bf16)v1.w;
      aQ[kk] = f;
    }
  }
  __syncthreads();

  // ---- S = Q K^T : 8 col-tiles x 4 k-steps ----
  f32x4 accS[8];
  #pragma unroll
  for (int n = 0; n < 8; n++) {
    f32x4 acc = {0.f, 0.f, 0.f, 0.f};
    #pragma unroll
    for (int kk = 0; kk < 4; kk++) {
      int row = n * 16 + l15;
      int c0 = lgp * 8 + kk * 32;
      bf16x8 bK = *(const bf16x8*)(sm + ((row * 128 + c0) ^ ((row & 7) << 3)));
      acc = __builtin_amdgcn_mfma_f32_16x16x32_bf16(aQ[kk], bK, acc, 0, 0, 0);
    }
    accS[n] = acc;
  }

  // ---- softmax per row (rows live in 16-lane groups; reduce via shfl_xor) ----
  float pval[8][4];
  float lsum[4];
  #pragma unroll
  for (int r = 0; r < 4; r++) {
    float mm = -1e30f;
    #pragma unroll
    for (int n = 0; n < 8; n++) {
      float lg2 = accS[n][r] * 0.03125f * (n < 4 ? sval : 1.0f);  // dim^-0.5 = 1/32
      pval[n][r] = lg2;
      mm = fmaxf(mm, lg2);
    }
    mm = fmaxf(mm, __shfl_xor(mm, 1));
    mm = fmaxf(mm, __shfl_xor(mm, 2));
    mm = fmaxf(mm, __shfl_xor(mm, 4));
    mm = fmaxf(mm, __shfl_xor(mm, 8));
    float ss = 0.f;
    #pragma unroll
    for (int n = 0; n < 8; n++) {
      float p = __expf(pval[n][r] - mm);
      ss += p;
      pval[n][r] = p * (n < 4 ? sval : 1.0f);   // fold V-side scale post-softmax
    }
    ss += __shfl_xor(ss, 1);
    ss += __shfl_xor(ss, 2);
    ss += __shfl_xor(ss, 4);
    ss += __shfl_xor(ss, 8);
    lsum[r] = ss;
  }

  __syncthreads();   // all waves done reading Kb before P overwrites it

  // ---- write P (bf16) into Kb region; wave w rows 16w..16w+15 only ----
  #pragma unroll
  for (int n = 0; n < 8; n++) {
    #pragma unroll
    for (int r = 0; r < 4; r++) {
      int prow = w * 16 + lgp * 4 + r;
      int pcol = n * 16 + l15;
      sm[(prow * 128 + pcol) ^ ((prow & 7) << 3)] = f2bf(pval[n][r]);
    }
  }

  // ---- O = P V  (A = own-wave P rows, B = Vt) ----
  bf16x8 aP[4];
  #pragma unroll
  for (int kk = 0; kk < 4; kk++) {
    int prow = w * 16 + l15;
    int c0 = lgp * 8 + kk * 32;
    aP[kk] = *(const bf16x8*)(sm + ((prow * 128 + c0) ^ ((prow & 7) << 3)));
  }
  float invl[4];
  #pragma unroll
  for (int r = 0; r < 4; r++) invl[r] = 1.0f / lsum[r];

  #pragma unroll
  for (int n = 0; n < 8; n++) {
    f32x4 acc = {0.f, 0.f, 0.f, 0.f};
    #pragma unroll
    for (int kk = 0; kk < 4; kk++) {
      int d = n * 16 + l15;
      int j0 = lgp * 8 + kk * 32;
      bf16x8 bV = *(const bf16x8*)(sm + 16384 + ((d * 128 + j0) ^ ((d & 7) << 3)));
      acc = __builtin_amdgcn_mfma_f32_16x16x32_bf16(aP[kk], bV, acc, 0, 0, 0);
    }
    #pragma unroll
    for (int r = 0; r < 4; r++) {
      int i = w * 16 + lgp * 4 + r;
      int d = n * 16 + l15;
      out[((size_t)bh * T_SEQ + (size_t)u * BSZ + i) * DH + d] = acc[r] * invl[r];
    }
  }
}

// ---------------------------------------------------------------------------
extern "C" void kernel_launch(void* const* d_in, const int* in_sizes, int n_in,
                              void* d_out, int out_size, void* d_ws, size_t ws_size,
                              hipStream_t stream) {
  (void)in_sizes; (void)n_in; (void)out_size; (void)ws_size;
  const float* q  = (const float*)d_in[0];
  const float* k  = (const float*)d_in[1];
  const float* v  = (const float*)d_in[2];
  const float* W  = (const float*)d_in[3];
  const float* ug = (const float*)d_in[4];
  float* out = (float*)d_out;

  float* rbuf = (float*)d_ws;                                   // 16*128*128 f32 = 1 MB
  int*   idxb = (int*)((char*)d_ws + (size_t)NBH * NBUCK * NBUCK * 4);
  float* sb   = (float*)((char*)idxb + (size_t)NBH * NBUCK * 4);

  k_sortnet<<<dim3(NBUCK, NBH), 256, 0, stream>>>(q, k, W, ug, rbuf);
  k_sinkhorn<<<NBH, 512, 0, stream>>>(rbuf, idxb, sb);
  k_attn<<<dim3(NBUCK, NBH), 256, 0, stream>>>(q, k, v, idxb, sb, out);
}

// Round 2
// 121.113 us; speedup vs baseline: 1.1952x; 1.1952x over previous
//
#include <hip/hip_runtime.h>
#include <hip/hip_bf16.h>

// Shapes (fixed by reference): b=2, h=8, t=8192, dh=128
#define T_SEQ   8192
#define DH      128
#define NBH     16
#define NBUCK   128
#define BSZ     64
#define EPSF    1e-6f

// 16B-granular XOR swizzle (keeps b128 reads contiguous), spreads 32 rows
// over 8 x 16B slots even when the writing lane's row-stride is 4.
#define SWZ(r) (((((r) & 7) ^ (((r) >> 3) & 7))) << 3)

typedef __attribute__((ext_vector_type(8))) __bf16 bf16x8;
typedef __attribute__((ext_vector_type(4))) float  f32x4;

static __device__ __forceinline__ unsigned short f2bf(float f) {
  __bf16 h = (__bf16)f;
  return __builtin_bit_cast(unsigned short, h);
}

// ---------------------------------------------------------------------------
// Kernel 1: bucket sums. grid (128, 16, 2[q|k]), 256 threads. Pure streaming.
// x[bh][u][e], e = which*128 + col.
// ---------------------------------------------------------------------------
__global__ __launch_bounds__(256) void k_bsum(
    const float* __restrict__ q, const float* __restrict__ k,
    float* __restrict__ x) {
  const int u = blockIdx.x, bh = blockIdx.y, which = blockIdx.z;
  const int t = threadIdx.x;
  const int c4g = t & 31;           // float4 column group 0..31
  const int r0  = (t >> 5) << 3;    // 8 rows per thread-row-group
  const float* src = which ? k : q;
  const float* p = src + ((size_t)bh * T_SEQ + (size_t)u * BSZ + r0) * DH + c4g * 4;
  float4 acc = {0.f, 0.f, 0.f, 0.f};
  #pragma unroll
  for (int r = 0; r < 8; r++) {
    float4 vv = *(const float4*)(p + (size_t)r * DH);
    acc.x += vv.x; acc.y += vv.y; acc.z += vv.z; acc.w += vv.w;
  }
  __shared__ float4 xr[8][32];
  xr[t >> 5][c4g] = acc;
  __syncthreads();
  if (t < 32) {
    float4 s4 = xr[0][t];
    #pragma unroll
    for (int j = 1; j < 8; j++) {
      float4 o = xr[j][t];
      s4.x += o.x; s4.y += o.y; s4.z += o.z; s4.w += o.w;
    }
    *(float4*)(x + ((size_t)bh * NBUCK + u) * 256 + which * 128 + t * 4) = s4;
  }
}

// ---------------------------------------------------------------------------
// Kernel 2: sortnet GEMM + relu + gumbel-log. grid (32, 16), 128 threads.
// 4 buckets per block (W re-read amortized; W stays in L2).
// ---------------------------------------------------------------------------
__global__ __launch_bounds__(128) void k_sortgemm(
    const float* __restrict__ x, const float* __restrict__ W,
    const float* __restrict__ ug, float* __restrict__ rbuf) {
  const int u0 = blockIdx.x * 4, bh = blockIdx.y;
  const int v = threadIdx.x;
  __shared__ float xs[4][256];
  for (int i = v; i < 1024; i += 128)
    xs[i >> 8][i & 255] = x[((size_t)bh * NBUCK + u0 + (i >> 8)) * 256 + (i & 255)];
  __syncthreads();
  const float* Wp = W + (size_t)(bh & 7) * 256 * NBUCK + v;
  float acc0 = 0.f, acc1 = 0.f, acc2 = 0.f, acc3 = 0.f;
  #pragma unroll 16
  for (int e = 0; e < 256; e++) {
    float we = Wp[(size_t)e * NBUCK];
    acc0 += xs[0][e] * we;
    acc1 += xs[1][e] * we;
    acc2 += xs[2][e] * we;
    acc3 += xs[3][e] * we;
  }
  float accs[4] = {acc0, acc1, acc2, acc3};
  #pragma unroll
  for (int j = 0; j < 4; j++) {
    float R = fmaxf(accs[j], 0.f) + EPSF;
    float gu = ug[((size_t)bh * NBUCK + u0 + j) * NBUCK + v] + EPSF;
    float g = -logf(-logf(gu) + EPSF);
    rbuf[((size_t)bh * NBUCK + u0 + j) * NBUCK + v] = (logf(R) + g) * (1.f / 0.75f);
  }
}

// ---------------------------------------------------------------------------
// Kernel 3: sinkhorn, 7 iters, offset form r_eff = r0 + ra[u] + ca[v].
// grid 16, 1024 threads: 8 lanes per row/col, shfl_xor reduces (2 barriers/it).
// Then per-row argmax -> idx, s.
// ---------------------------------------------------------------------------
__global__ __launch_bounds__(1024) void k_sinkhorn(
    const float* __restrict__ rbuf, int* __restrict__ idxb, float* __restrict__ sb) {
  const int bh = blockIdx.x;
  const int t  = threadIdx.x;
  const int g  = t >> 3;   // row (or col) 0..127
  const int s  = t & 7;    // 16-element segment
  __shared__ float rl[128 * 129];
  __shared__ float ca[128], ra[128];

  const float* rb = rbuf + (size_t)bh * (NBUCK * NBUCK);
  for (int i = t; i < NBUCK * NBUCK; i += 1024)
    rl[(i >> 7) * 129 + (i & 127)] = rb[i];
  if (t < 128) ca[t] = 0.f;
  __syncthreads();

  for (int iter = 0; iter < 7; iter++) {
    // row phase: ra[u] = -LSE_v(r0[u][v] + ca[v])
    {
      float vals[16];
      float m = -1e30f;
      #pragma unroll
      for (int i = 0; i < 16; i++) {
        int vv = s * 16 + i;
        vals[i] = rl[g * 129 + vv] + ca[vv];
        m = fmaxf(m, vals[i]);
      }
      m = fmaxf(m, __shfl_xor(m, 1));
      m = fmaxf(m, __shfl_xor(m, 2));
      m = fmaxf(m, __shfl_xor(m, 4));
      float ss = 0.f;
      #pragma unroll
      for (int i = 0; i < 16; i++) ss += __expf(vals[i] - m);
      ss += __shfl_xor(ss, 1);
      ss += __shfl_xor(ss, 2);
      ss += __shfl_xor(ss, 4);
      if (s == 0) ra[g] = -(m + logf(ss));
    }
    __syncthreads();
    // col phase: ca[v] = -LSE_u(r0[u][v] + ra[u])
    {
      float vals[16];
      float m = -1e30f;
      #pragma unroll
      for (int i = 0; i < 16; i++) {
        int uu = s * 16 + i;
        vals[i] = rl[uu * 129 + g] + ra[uu];
        m = fmaxf(m, vals[i]);
      }
      m = fmaxf(m, __shfl_xor(m, 1));
      m = fmaxf(m, __shfl_xor(m, 2));
      m = fmaxf(m, __shfl_xor(m, 4));
      float ss = 0.f;
      #pragma unroll
      for (int i = 0; i < 16; i++) ss += __expf(vals[i] - m);
      ss += __shfl_xor(ss, 1);
      ss += __shfl_xor(ss, 2);
      ss += __shfl_xor(ss, 4);
      if (s == 0) ca[g] = -(m + logf(ss));
    }
    __syncthreads();
  }

  // per-row argmax over v of r0 + ca[v] (first-index-on-tie like jnp.argmax)
  {
    float best = -1e30f; int bi = 0;
    #pragma unroll
    for (int i = 0; i < 16; i++) {
      int vv = s * 16 + i;
      float val = rl[g * 129 + vv] + ca[vv];
      if (val > best) { best = val; bi = vv; }
    }
    #pragma unroll
    for (int d = 1; d < 8; d <<= 1) {
      float ob = __shfl_xor(best, d);
      int   oi = __shfl_xor(bi, d);
      if (ob > best || (ob == best && oi < bi)) { best = ob; bi = oi; }
    }
    if (s == 0) {
      idxb[bh * NBUCK + g] = bi;
      sb[bh * NBUCK + g]   = expf(rl[g * 129 + bi] + ra[g] + ca[bi]);
    }
  }
}

// ---------------------------------------------------------------------------
// Kernel 4: per-bucket attention. grid (128,16), 256 threads (4 waves).
// 32 KB LDS -> 5 blocks/CU. Phases:
//   [0,16384)us: K(128x128 bf16, swz)   -> later P(64x128) at [0,8192)
//   [8192,16384)us: V half (Vt[d][jj], 128x64 bf16, swz), staged twice.
// V is prefetched to regs at kernel start (latency hidden under S+softmax).
// ---------------------------------------------------------------------------
__global__ __launch_bounds__(256) void k_attn(
    const float* __restrict__ q, const float* __restrict__ k, const float* __restrict__ v,
    const int* __restrict__ idxb, const float* __restrict__ sb, float* __restrict__ out) {
  const int u  = blockIdx.x;
  const int bh = blockIdx.y;
  const int t  = threadIdx.x;
  const int lane = t & 63;
  const int w  = t >> 6;          // wave 0..3, owns output rows 16w..16w+15
  const int l15 = lane & 15;
  const int lgp = lane >> 4;      // 0..3

  __shared__ uint4 smem4[2048];   // 32 KB
  unsigned short* sm = (unsigned short*)smem4;
  #define VOFF 8192

  const int   vidx = idxb[bh * NBUCK + u];
  const float sval = sb[bh * NBUCK + u];
  const size_t hb = (size_t)bh * (T_SEQ * DH);
  const float* qg = q + hb;
  const float* kg = k + hb;
  const float* vg = v + hb;

  // ---- stage K rows (0..63 = vidx bucket, 64..127 = u bucket), swizzled ----
  #pragma unroll
  for (int it = 0; it < 16; it++) {
    int i = it * 256 + t;
    int row = i >> 5;
    int c4 = (i & 31) << 2;
    int grow = (row < 64) ? (vidx * BSZ + row) : (u * BSZ + (row - 64));
    float4 val = *(const float4*)(kg + (size_t)grow * DH + c4);
    ushort4 hh;
    hh.x = f2bf(val.x); hh.y = f2bf(val.y); hh.z = f2bf(val.z); hh.w = f2bf(val.w);
    *(ushort4*)(sm + (((row * 128 + c4) ^ SWZ(row)))) = hh;
  }

  // ---- Q A-fragments direct global -> reg ----
  bf16x8 aQ[4];
  {
    int qrow = u * BSZ + w * 16 + l15;
    const float* qp = qg + (size_t)qrow * DH + lgp * 8;
    #pragma unroll
    for (int kk = 0; kk < 4; kk++) {
      float4 v0 = *(const float4*)(qp + kk * 32);
      float4 v1 = *(const float4*)(qp + kk * 32 + 4);
      bf16x8 f;
      f[0] = (__bf16)v0.x; f[1] = (__bf16)v0.y; f[2] = (__bf16)v0.z; f[3] = (__bf16)v0.w;
      f[4] = (__bf16)v1.x; f[5] = (__bf16)v1.y; f[6] = (__bf16)v1.z; f[7] = (__bf16)v1.w;
      aQ[kk] = f;
    }
  }

  // ---- prefetch BOTH V halves into registers (T14: hide HBM latency) ----
  float4 vpre1[8], vpre2[8];
  #pragma unroll
  for (int it = 0; it < 8; it++) {
    int i = it * 256 + t;
    int d0 = (i & 31) << 2;
    int j  = i >> 5;                          // 0..63
    vpre1[it] = *(const float4*)(vg + (size_t)(vidx * BSZ + j) * DH + d0);
    vpre2[it] = *(const float4*)(vg + (size_t)(u    * BSZ + j) * DH + d0);
  }
  __syncthreads();   // B1: K staged

  // ---- S = Q K^T ----
  f32x4 accS[8];
  #pragma unroll
  for (int n = 0; n < 8; n++) {
    f32x4 acc = {0.f, 0.f, 0.f, 0.f};
    #pragma unroll
    for (int kk = 0; kk < 4; kk++) {
      int row = n * 16 + l15;
      int c0 = lgp * 8 + kk * 32;
      bf16x8 bK = *(const bf16x8*)(sm + ((row * 128 + c0) ^ SWZ(row)));
      acc = __builtin_amdgcn_mfma_f32_16x16x32_bf16(aQ[kk], bK, acc, 0, 0, 0);
    }
    accS[n] = acc;
  }

  // ---- softmax per row (rows in 16-lane groups; shfl_xor reduce) ----
  float pval[8][4];
  float lsum[4];
  #pragma unroll
  for (int r = 0; r < 4; r++) {
    float mm = -1e30f;
    #pragma unroll
    for (int n = 0; n < 8; n++) {
      float lg2 = accS[n][r] * 0.03125f * (n < 4 ? sval : 1.0f);  // dim^-0.5 = 1/32
      pval[n][r] = lg2;
      mm = fmaxf(mm, lg2);
    }
    mm = fmaxf(mm, __shfl_xor(mm, 1));
    mm = fmaxf(mm, __shfl_xor(mm, 2));
    mm = fmaxf(mm, __shfl_xor(mm, 4));
    mm = fmaxf(mm, __shfl_xor(mm, 8));
    float ss = 0.f;
    #pragma unroll
    for (int n = 0; n < 8; n++) {
      float p = __expf(pval[n][r] - mm);
      ss += p;
      pval[n][r] = p * (n < 4 ? sval : 1.0f);   // fold V-side scale post-softmax
    }
    ss += __shfl_xor(ss, 1);
    ss += __shfl_xor(ss, 2);
    ss += __shfl_xor(ss, 4);
    ss += __shfl_xor(ss, 8);
    lsum[r] = ss;
  }

  __syncthreads();   // B2: all waves done reading K

  // ---- write P (own wave rows) into [0,8192) ----
  #pragma unroll
  for (int n = 0; n < 8; n++) {
    #pragma unroll
    for (int r = 0; r < 4; r++) {
      int prow = w * 16 + lgp * 4 + r;
      int pcol = n * 16 + l15;
      sm[(prow * 128 + pcol) ^ SWZ(prow)] = f2bf(pval[n][r]);
    }
  }
  // ---- V half 1 (j=0..63: vidx bucket) from regs -> [VOFF, +8192) ----
  #pragma unroll
  for (int it = 0; it < 8; it++) {
    int i = it * 256 + t;
    int d0 = (i & 31) << 2;
    int j  = i >> 5;
    float4 val = vpre1[it];
    sm[VOFF + (((d0 + 0) * 64 + j) ^ SWZ(d0 + 0))] = f2bf(val.x);
    sm[VOFF + (((d0 + 1) * 64 + j) ^ SWZ(d0 + 1))] = f2bf(val.y);
    sm[VOFF + (((d0 + 2) * 64 + j) ^ SWZ(d0 + 2))] = f2bf(val.z);
    sm[VOFF + (((d0 + 3) * 64 + j) ^ SWZ(d0 + 3))] = f2bf(val.w);
  }
  __syncthreads();   // B3: Vh1 + P ready

  // ---- aP fragments (all 4 k-slices; P complete) ----
  bf16x8 aP[4];
  #pragma unroll
  for (int kk = 0; kk < 4; kk++) {
    int prow = w * 16 + l15;
    int c0 = lgp * 8 + kk * 32;
    aP[kk] = *(const bf16x8*)(sm + ((prow * 128 + c0) ^ SWZ(prow)));
  }

  // ---- PV part 1 (j = 0..63) ----
  f32x4 accO[8];
  #pragma unroll
  for (int n = 0; n < 8; n++) {
    f32x4 acc = {0.f, 0.f, 0.f, 0.f};
    #pragma unroll
    for (int kk = 0; kk < 2; kk++) {
      int d = n * 16 + l15;
      int jj0 = lgp * 8 + kk * 32;
      bf16x8 bV = *(const bf16x8*)(sm + VOFF + ((d * 64 + jj0) ^ SWZ(d)));
      acc = __builtin_amdgcn_mfma_f32_16x16x32_bf16(aP[kk], bV, acc, 0, 0, 0);
    }
    accO[n] = acc;
  }
  __syncthreads();   // B4: done reading Vh1

  // ---- V half 2 (j=64..127: u bucket) from regs ----
  #pragma unroll
  for (int it = 0; it < 8; it++) {
    int i = it * 256 + t;
    int d0 = (i & 31) << 2;
    int j  = i >> 5;
    float4 val = vpre2[it];
    sm[VOFF + (((d0 + 0) * 64 + j) ^ SWZ(d0 + 0))] = f2bf(val.x);
    sm[VOFF + (((d0 + 1) * 64 + j) ^ SWZ(d0 + 1))] = f2bf(val.y);
    sm[VOFF + (((d0 + 2) * 64 + j) ^ SWZ(d0 + 2))] = f2bf(val.z);
    sm[VOFF + (((d0 + 3) * 64 + j) ^ SWZ(d0 + 3))] = f2bf(val.w);
  }
  __syncthreads();   // B5: Vh2 ready

  float invl[4];
  #pragma unroll
  for (int r = 0; r < 4; r++) invl[r] = 1.0f / lsum[r];

  // ---- PV part 2 (j = 64..127) + store ----
  #pragma unroll
  for (int n = 0; n < 8; n++) {
    f32x4 acc = accO[n];
    #pragma unroll
    for (int kk = 2; kk < 4; kk++) {
      int d = n * 16 + l15;
      int jj0 = lgp * 8 + (kk - 2) * 32;
      bf16x8 bV = *(const bf16x8*)(sm + VOFF + ((d * 64 + jj0) ^ SWZ(d)));
      acc = __builtin_amdgcn_mfma_f32_16x16x32_bf16(aP[kk], bV, acc, 0, 0, 0);
    }
    #pragma unroll
    for (int r = 0; r < 4; r++) {
      int i2 = w * 16 + lgp * 4 + r;
      int d = n * 16 + l15;
      out[((size_t)bh * T_SEQ + (size_t)u * BSZ + i2) * DH + d] = acc[r] * invl[r];
    }
  }
}

// ---------------------------------------------------------------------------
extern "C" void kernel_launch(void* const* d_in, const int* in_sizes, int n_in,
                              void* d_out, int out_size, void* d_ws, size_t ws_size,
                              hipStream_t stream) {
  (void)in_sizes; (void)n_in; (void)out_size; (void)ws_size;
  const float* q  = (const float*)d_in[0];
  const float* k  = (const float*)d_in[1];
  const float* v  = (const float*)d_in[2];
  const float* W  = (const float*)d_in[3];
  const float* ug = (const float*)d_in[4];
  float* out = (float*)d_out;

  float* xbuf = (float*)d_ws;                                  // 16*128*256 f32 = 2 MB
  float* rbuf = xbuf + (size_t)NBH * NBUCK * 256;              // 1 MB
  int*   idxb = (int*)(rbuf + (size_t)NBH * NBUCK * NBUCK);
  float* sb   = (float*)(idxb + NBH * NBUCK);

  k_bsum    <<<dim3(NBUCK, NBH, 2), 256, 0, stream>>>(q, k, xbuf);
  k_sortgemm<<<dim3(32, NBH),       128, 0, stream>>>(xbuf, W, ug, rbuf);
  k_sinkhorn<<<NBH,                1024, 0, stream>>>(rbuf, idxb, sb);
  k_attn    <<<dim3(NBUCK, NBH),    256, 0, stream>>>(q, k, v, idxb, sb, out);
}